// Round 12
// baseline (570.459 us; speedup 1.0000x reference)
//
#include <hip/hip_runtime.h>

// SkipLSTM: B=256, T=784, I=1, H=110, NCLS=10
// R12 = R11 verbatim (4 waves, 1 wave/SIMD, quad owns 2 units, verified
// absmax 0.001) with the MAC engine swapped: v_dot2_f32_f16 is HALF-rate
// (4cyc / 2 MACs -- the busy-cycle model across R8/R10/R11 pins it), while
// packed f16 FMA is full-rate (2cyc / 2 MACs, f16 vector peak = 2x fp32).
// Rows accumulate in h2 via compiler-emitted v_pk_fma_f16
// (__builtin_elementwise_fma; NO asm "v" constraints so AGPR-resident
// weights are read directly -- R5's copy-storm lesson), folded once per row
// with fdot2(acc, {1,1}, bias+x-term). Dot block: 448 -> ~256 cyc/SIMD.
// Everything else identical: quad reduce (2 DPP), lane-j-activates-gate-j,
// qbcast redistribute, bias on quad-lane 0 only, du pipelined, one
// barrier/step, h(f16)+p double-buffered.

#define T784 784
#define H110 110
#define NT   256
#define NCLS 10
#define LOG2E 1.44269504088896340736f

typedef _Float16 h2 __attribute__((ext_vector_type(2)));
typedef _Float16 h4 __attribute__((ext_vector_type(4)));

__device__ __forceinline__ float frcp(float x)  { return __builtin_amdgcn_rcpf(x); }
__device__ __forceinline__ float fexp2(float x) { return __builtin_amdgcn_exp2f(x); }

// single-instruction DPP adds (src0 carries the DPP swizzle)
__device__ __forceinline__ float add_q1(float v) {  // xor1 within quad
    float d; asm("v_add_f32_dpp %0, %1, %1 quad_perm:[1,0,3,2] row_mask:0xf bank_mask:0xf bound_ctrl:0"
                 : "=v"(d) : "v"(v)); return d;
}
__device__ __forceinline__ float add_q2(float v) {  // xor2 within quad
    float d; asm("v_add_f32_dpp %0, %1, %1 quad_perm:[2,3,0,1] row_mask:0xf bank_mask:0xf bound_ctrl:0"
                 : "=v"(d) : "v"(v)); return d;
}
__device__ __forceinline__ float add_hm(float v) {  // xor4 (row_half_mirror)
    float d; asm("v_add_f32_dpp %0, %1, %1 row_half_mirror row_mask:0xf bank_mask:0xf bound_ctrl:0"
                 : "=v"(d) : "v"(v)); return d;
}
__device__ __forceinline__ float add_rm(float v) {  // xor8 (row_mirror)
    float d; asm("v_add_f32_dpp %0, %1, %1 row_mirror row_mask:0xf bank_mask:0xf bound_ctrl:0"
                 : "=v"(d) : "v"(v)); return d;
}
__device__ __forceinline__ float add_b15(float v) { // row_bcast:15
    float d; asm("v_add_f32_dpp %0, %1, %1 row_bcast:15 row_mask:0xf bank_mask:0xf bound_ctrl:0"
                 : "=v"(d) : "v"(v)); return d;
}
__device__ __forceinline__ float add_b31(float v) { // row_bcast:31
    float d; asm("v_add_f32_dpp %0, %1, %1 row_bcast:31 row_mask:0xf bank_mask:0xf bound_ctrl:0"
                 : "=v"(d) : "v"(v)); return d;
}
template <int L>
__device__ __forceinline__ float qbcast(float v) {  // broadcast quad-lane L
    float d;
    if (L == 0) asm("v_mov_b32_dpp %0, %1 quad_perm:[0,0,0,0] row_mask:0xf bank_mask:0xf bound_ctrl:0" : "=v"(d) : "v"(v));
    if (L == 1) asm("v_mov_b32_dpp %0, %1 quad_perm:[1,1,1,1] row_mask:0xf bank_mask:0xf bound_ctrl:0" : "=v"(d) : "v"(v));
    if (L == 2) asm("v_mov_b32_dpp %0, %1 quad_perm:[2,2,2,2] row_mask:0xf bank_mask:0xf bound_ctrl:0" : "=v"(d) : "v"(v));
    if (L == 3) asm("v_mov_b32_dpp %0, %1 quad_perm:[3,3,3,3] row_mask:0xf bank_mask:0xf bound_ctrl:0" : "=v"(d) : "v"(v));
    return d;
}

__global__ __launch_bounds__(NT, 1)
void skiplstm_kernel(const float* __restrict__ x,
                     const float* __restrict__ W_ih,
                     const float* __restrict__ W_hh,
                     const float* __restrict__ b,
                     const float* __restrict__ W_p,
                     const float* __restrict__ b_p,
                     const float* __restrict__ h0,
                     const float* __restrict__ c0,
                     const float* __restrict__ W_fc,
                     const float* __restrict__ b_fc,
                     float* __restrict__ out)
{
    __shared__ __align__(16) _Float16 s_h16[256]; // double-buffered h f16 (128 each)
    __shared__ float s_pbuf[256];                 // double-buffered c*W_p' partials
    __shared__ float s_x[T784];

    const int tid  = threadIdx.x;
    const int bb   = blockIdx.x;
    const int q    = tid >> 2;                   // quad id: 0..63 (55..63 inactive)
    const int j    = tid & 3;                    // k-slice lane
    const int uA   = 2 * q;                      // first unit of this quad
    const int uB   = 2 * q + 1;                  // second unit
    const bool qact = (q < 55);                  // both units valid iff q<55

    // ---- f16 weight pairs for BOTH units, pre-scaled by -LOG2E (g: -2LOG2E) ----
    h2 w2A[4][14], w2B[4][14];
    float bvA[4], wvA[4], bvB[4], wvB[4];
    #pragma unroll
    for (int g = 0; g < 4; ++g) {
        const float ws = (g == 2) ? (-2.0f * LOG2E) : (-LOG2E);
        const int rowA = uA + H110 * g;
        const int rowB = uB + H110 * g;
        // bias/x-term on quad-lane 0 only (counted once post-reduce)
        bvA[g] = (qact && j == 0) ? b[rowA]    * ws : 0.0f;
        wvA[g] = (qact && j == 0) ? W_ih[rowA] * ws : 0.0f;
        bvB[g] = (qact && j == 0) ? b[rowB]    * ws : 0.0f;
        wvB[g] = (qact && j == 0) ? W_ih[rowB] * ws : 0.0f;
        const float* rpA = W_hh + rowA * H110;
        const float* rpB = W_hh + rowB * H110;
        #pragma unroll
        for (int m = 0; m < 14; ++m) {
            const int k = 28 * j + 2 * m;
            float a0 = 0.f, a1 = 0.f, b0 = 0.f, b1 = 0.f;
            if (qact) {
                if (k + 0 < H110) { a0 = rpA[k + 0] * ws; b0 = rpB[k + 0] * ws; }
                if (k + 1 < H110) { a1 = rpA[k + 1] * ws; b1 = rpB[k + 1] * ws; }
            }
            w2A[g][m].x = (_Float16)a0; w2A[g][m].y = (_Float16)a1;
            w2B[g][m].x = (_Float16)b0; w2B[g][m].y = (_Float16)b1;
        }
    }
    float cregA = qact ? c0[uA] : 0.0f;          // f32 state, replicated in quad
    float hregA = qact ? h0[uA] : 0.0f;
    float cregB = qact ? c0[uB] : 0.0f;
    float hregB = qact ? h0[uB] : 0.0f;
    const float wpnA = qact ? (-LOG2E) * W_p[uA] : 0.0f;  // pre-scaled
    const float wpnB = qact ? (-LOG2E) * W_p[uB] : 0.0f;
    const float bpn  = (-LOG2E) * b_p[0];

    // lane j activates gate j; gate 2 (g) is tanh = 2*sigm(2x)-1
    const float mulc = (j == 2) ? 2.0f : 1.0f;
    const float addc = (j == 2) ? -1.0f : 0.0f;
    const h2 one2 = {(_Float16)1.0f, (_Float16)1.0f};  // fdot2 fold vector
    const h2 zero2 = {(_Float16)0.0f, (_Float16)0.0f};

    for (int i = tid; i < 256;  i += NT) { s_h16[i] = (_Float16)0.f; s_pbuf[i] = 0.0f; }
    for (int i = tid; i < T784; i += NT) s_x[i] = x[bb * T784 + i];
    __syncthreads();
    if (tid < H110) s_h16[tid] = (_Float16)h0[tid];  // buf0 init
    __syncthreads();

    float u_prev = 1.0f;                         // replicated per-wave (identical)
    int   cnt    = 0;

    auto step = [&](const _Float16* hb, _Float16* hn,
                    const float* pp, float* pn, int t, bool first) {
        // ---- p-reads FIRST (du math hides under the h-read latency) ----
        const int lane = tid & 63;
        const float p0 = pp[lane], p1 = pp[lane + 64];
        const float xt = s_x[t];
        const h4* hp = (const h4*)hb + 7 * j;    // f16 [28j, 28j+28), shared A/B
        const h4 hh0 = hp[0], hh1 = hp[1], hh2 = hp[2], hh3 = hp[3];
        const h4 hh4 = hp[4], hh5 = hp[5], hh6 = hp[6];

        h2 hv[14];
        hv[0]  = __builtin_shufflevector(hh0, hh0, 0, 1);
        hv[1]  = __builtin_shufflevector(hh0, hh0, 2, 3);
        hv[2]  = __builtin_shufflevector(hh1, hh1, 0, 1);
        hv[3]  = __builtin_shufflevector(hh1, hh1, 2, 3);
        hv[4]  = __builtin_shufflevector(hh2, hh2, 0, 1);
        hv[5]  = __builtin_shufflevector(hh2, hh2, 2, 3);
        hv[6]  = __builtin_shufflevector(hh3, hh3, 0, 1);
        hv[7]  = __builtin_shufflevector(hh3, hh3, 2, 3);
        hv[8]  = __builtin_shufflevector(hh4, hh4, 0, 1);
        hv[9]  = __builtin_shufflevector(hh4, hh4, 2, 3);
        hv[10] = __builtin_shufflevector(hh5, hh5, 0, 1);
        hv[11] = __builtin_shufflevector(hh5, hh5, 2, 3);
        hv[12] = __builtin_shufflevector(hh6, hh6, 0, 1);
        hv[13] = __builtin_shufflevector(hh6, hh6, 2, 3);

        // ---- 112 v_pk_fma_f16 (full-rate) + 8 fdot2 folds ----
        h2 sA0 = zero2, sA1 = zero2, sA2 = zero2, sA3 = zero2;
        h2 sB0 = zero2, sB1 = zero2, sB2 = zero2, sB3 = zero2;
        #pragma unroll
        for (int m = 0; m < 14; ++m) {
            sA0 = __builtin_elementwise_fma(hv[m], w2A[0][m], sA0);
            sA1 = __builtin_elementwise_fma(hv[m], w2A[1][m], sA1);
            sA2 = __builtin_elementwise_fma(hv[m], w2A[2][m], sA2);
            sA3 = __builtin_elementwise_fma(hv[m], w2A[3][m], sA3);
            sB0 = __builtin_elementwise_fma(hv[m], w2B[0][m], sB0);
            sB1 = __builtin_elementwise_fma(hv[m], w2B[1][m], sB1);
            sB2 = __builtin_elementwise_fma(hv[m], w2B[2][m], sB2);
            sB3 = __builtin_elementwise_fma(hv[m], w2B[3][m], sB3);
        }
        float a0 = __builtin_amdgcn_fdot2(sA0, one2, fmaf(xt, wvA[0], bvA[0]), false);
        float a1 = __builtin_amdgcn_fdot2(sA1, one2, fmaf(xt, wvA[1], bvA[1]), false);
        float a2 = __builtin_amdgcn_fdot2(sA2, one2, fmaf(xt, wvA[2], bvA[2]), false);
        float a3 = __builtin_amdgcn_fdot2(sA3, one2, fmaf(xt, wvA[3], bvA[3]), false);
        float b0 = __builtin_amdgcn_fdot2(sB0, one2, fmaf(xt, wvB[0], bvB[0]), false);
        float b1 = __builtin_amdgcn_fdot2(sB1, one2, fmaf(xt, wvB[1], bvB[1]), false);
        float b2 = __builtin_amdgcn_fdot2(sB2, one2, fmaf(xt, wvB[2], bvB[2]), false);
        float b3 = __builtin_amdgcn_fdot2(sB3, one2, fmaf(xt, wvB[3], bvB[3]), false);

        // ---- pipelined du_{t-1} -> u_t (hidden under the fma block) ----
        float u_now;
        if (first) {
            u_now = 1.0f;                        // u0 = 1
        } else {
            float v = p0 + p1;
            v = add_q1(v); v = add_q2(v); v = add_hm(v);
            v = add_rm(v); v = add_b15(v); v = add_b31(v);
            const float tot = __int_as_float(
                __builtin_amdgcn_readlane(__float_as_int(v), 63));
            const float du = frcp(1.0f + fexp2(tot + bpn));      // sigm
            u_now = (u_prev > 0.5f) ? du
                                    : (u_prev + fminf(du, 1.0f - u_prev));
        }
        const bool up = u_now > 0.5f;            // == round-half-even on [0,1]
        cnt += up ? 1 : 0;
        u_prev = u_now;

        // ---- quad allreduce, unit A then unit B (2 DPP levels each) ----
        a0 = add_q1(a0); a1 = add_q1(a1); a2 = add_q1(a2); a3 = add_q1(a3);
        b0 = add_q1(b0); b1 = add_q1(b1); b2 = add_q1(b2); b3 = add_q1(b3);
        a0 = add_q2(a0); a1 = add_q2(a1); a2 = add_q2(a2); a3 = add_q2(a3);
        b0 = add_q2(b0); b1 = add_q2(b1); b2 = add_q2(b2); b3 = add_q2(b3);

        // ---- lane j activates gate j of each unit (independent trans paths) ----
        const float tA01  = (j & 1) ? a1 : a0;
        const float tA23  = (j & 1) ? a3 : a2;
        const float aselA = (j & 2) ? tA23 : tA01;
        const float tB01  = (j & 1) ? b1 : b0;
        const float tB23  = (j & 1) ? b3 : b2;
        const float aselB = (j & 2) ? tB23 : tB01;
        const float avA = fmaf(mulc, frcp(1.0f + fexp2(aselA)), addc);
        const float avB = fmaf(mulc, frcp(1.0f + fexp2(aselB)), addc);
        const float giA = qbcast<0>(avA);
        const float gfA = qbcast<1>(avA);
        const float ggA = qbcast<2>(avA);
        const float goA = qbcast<3>(avA);
        const float giB = qbcast<0>(avB);
        const float gfB = qbcast<1>(avB);
        const float ggB = qbcast<2>(avB);
        const float goB = qbcast<3>(avB);

        const float cnA = fmaf(gfA, cregA, giA * ggA);
        const float cnB = fmaf(gfB, cregB, giB * ggB);
        const float thA = fmaf(2.0f, frcp(1.0f + fexp2(cnA * (-2.0f * LOG2E))), -1.0f);
        const float thB = fmaf(2.0f, frcp(1.0f + fexp2(cnB * (-2.0f * LOG2E))), -1.0f);
        const float hnA = goA * thA;
        const float hnB = goB * thB;
        cregA = up ? cnA : cregA;                // ub is exactly 0/1
        hregA = up ? hnA : hregA;
        cregB = up ? cnB : cregB;
        hregB = up ? hnB : hregB;
        if (qact && j == 0) {
            hn[uA] = (_Float16)hregA;            // lane 0 publishes unit A
            pn[uA] = cregA * wpnA;
        }
        if (qact && j == 1) {
            hn[uB] = (_Float16)hregB;            // lane 1 publishes unit B
            pn[uB] = cregB * wpnB;
        }
        __syncthreads();                         // the ONLY barrier per step
    };

    _Float16* const h0b = s_h16;
    _Float16* const h1b = s_h16 + 128;
    float* const p0b = s_pbuf;
    float* const p1b = s_pbuf + 128;

    step(h0b, h1b, p0b, p1b, 0, true);           // peeled: no du before step 0
    step(h1b, h0b, p1b, p0b, 1, false);
    step(h0b, h1b, p0b, p1b, 2, false);
    step(h1b, h0b, p1b, p0b, 3, false);
    for (int t = 4; t < T784; t += 4) {
        step(h0b, h1b, p0b, p1b, t,     false);
        step(h1b, h0b, p1b, p0b, t + 1, false);
        step(h0b, h1b, p0b, p1b, t + 2, false);
        step(h1b, h0b, p1b, p0b, t + 3, false);
    }

    // epilogue: final h is in buffer 0 (t=783 writes buf 0)
    if (tid < NCLS) {
        float acc = b_fc[tid];
        for (int k = 0; k < H110; ++k)
            acc = fmaf((float)s_h16[k], W_fc[tid * H110 + k], acc);
        out[bb * NCLS + tid] = acc;
    }
    if (tid == 0)
        atomicAdd(out + 256 * NCLS, (float)cnt); // total_u at flat index 2560
}

__global__ void zero_tail_kernel(float* out) {
    if (threadIdx.x == 0) out[256 * NCLS] = 0.0f;   // d_out is poisoned 0xAA
}

extern "C" void kernel_launch(void* const* d_in, const int* in_sizes, int n_in,
                              void* d_out, int out_size, void* d_ws, size_t ws_size,
                              hipStream_t stream) {
    const float* x    = (const float*)d_in[0];
    const float* W_ih = (const float*)d_in[1];
    const float* W_hh = (const float*)d_in[2];
    const float* b    = (const float*)d_in[3];
    const float* W_p  = (const float*)d_in[4];
    const float* b_p  = (const float*)d_in[5];
    const float* h0   = (const float*)d_in[6];
    const float* c0   = (const float*)d_in[7];
    const float* W_fc = (const float*)d_in[8];
    const float* b_fc = (const float*)d_in[9];
    float* out = (float*)d_out;

    zero_tail_kernel<<<1, 64, 0, stream>>>(out);
    skiplstm_kernel<<<256, NT, 0, stream>>>(x, W_ih, W_hh, b, W_p, b_p,
                                            h0, c0, W_fc, b_fc, out);
}

// Round 13
// 520.970 us; speedup vs baseline: 1.0950x; 1.0950x over previous
//
#include <hip/hip_runtime.h>

// SkipLSTM: B=256, T=784, I=1, H=110, NCLS=10
// R13: the GEMV goes to the MATRIX CORE. After R8-R12, the VALU MAC block
// has a hard ~450cyc/SIMD/step floor; v_mfma_f32_16x16x32_f16 does the same
// work in 28 mfma/wave ~= 140 cyc.
// Layout trick: permute W rows so tile t = units 4t..4t+3 x gates 0..3
// (row 4a+g in tile = unit 4t+a, gate g). Broadcast h into ALL 16 B columns
// (B[k=quad*8+j][n=lane&15]; every lane loads the per-quad k-slice) -> all
// C columns identical -> C[row=4*q4+reg] means EVERY lane holds unit
// (4t+q4)'s 4 gates in its 4 acc regs. Lane n<7 owns tile n: in-wave
// select (6 cmp + 24 cndmask), activations, c/h update, publish -- no
// cross-lane redistribution, no extra barrier.
// Skeleton from R11 (verified): 4 waves, 1/wave/SIMD, one barrier/step,
// h(f16)+p double-buffered, du pipelined under the mfma block, weights
// pre-scaled by -LOG2E (-2LOG2E for g-gate), bias counted once.

#define T784 784
#define H110 110
#define NT   256
#define NCLS 10
#define LOG2E 1.44269504088896340736f

typedef _Float16 v8h __attribute__((ext_vector_type(8)));
typedef float    v4f __attribute__((ext_vector_type(4)));

__device__ __forceinline__ float frcp(float x)  { return __builtin_amdgcn_rcpf(x); }
__device__ __forceinline__ float fexp2(float x) { return __builtin_amdgcn_exp2f(x); }

// single-instruction DPP adds for the du wave-reduction
__device__ __forceinline__ float add_q1(float v) {
    float d; asm("v_add_f32_dpp %0, %1, %1 quad_perm:[1,0,3,2] row_mask:0xf bank_mask:0xf bound_ctrl:0"
                 : "=v"(d) : "v"(v)); return d;
}
__device__ __forceinline__ float add_q2(float v) {
    float d; asm("v_add_f32_dpp %0, %1, %1 quad_perm:[2,3,0,1] row_mask:0xf bank_mask:0xf bound_ctrl:0"
                 : "=v"(d) : "v"(v)); return d;
}
__device__ __forceinline__ float add_hm(float v) {
    float d; asm("v_add_f32_dpp %0, %1, %1 row_half_mirror row_mask:0xf bank_mask:0xf bound_ctrl:0"
                 : "=v"(d) : "v"(v)); return d;
}
__device__ __forceinline__ float add_rm(float v) {
    float d; asm("v_add_f32_dpp %0, %1, %1 row_mirror row_mask:0xf bank_mask:0xf bound_ctrl:0"
                 : "=v"(d) : "v"(v)); return d;
}
__device__ __forceinline__ float add_b15(float v) {
    float d; asm("v_add_f32_dpp %0, %1, %1 row_bcast:15 row_mask:0xf bank_mask:0xf bound_ctrl:0"
                 : "=v"(d) : "v"(v)); return d;
}
__device__ __forceinline__ float add_b31(float v) {
    float d; asm("v_add_f32_dpp %0, %1, %1 row_bcast:31 row_mask:0xf bank_mask:0xf bound_ctrl:0"
                 : "=v"(d) : "v"(v)); return d;
}

__global__ __launch_bounds__(NT, 1)
void skiplstm_kernel(const float* __restrict__ x,
                     const float* __restrict__ W_ih,
                     const float* __restrict__ W_hh,
                     const float* __restrict__ b,
                     const float* __restrict__ W_p,
                     const float* __restrict__ b_p,
                     const float* __restrict__ h0,
                     const float* __restrict__ c0,
                     const float* __restrict__ W_fc,
                     const float* __restrict__ b_fc,
                     float* __restrict__ out)
{
    __shared__ __align__(16) _Float16 s_h16[256]; // 2 x 128 f16, pads stay 0
    __shared__ float s_pbuf[256];                 // 2 x 128 f32, pads stay 0
    __shared__ float s_x[T784];

    const int tid = threadIdx.x;
    const int bb  = blockIdx.x;
    const int w   = tid >> 6;                    // wave 0..3
    const int l   = tid & 63;
    const int q4  = l >> 4;                      // 0..3 (k-quad / C row group)
    const int m16 = l & 15;                      // A row within tile / C col
    const int aoff = m16 >> 2;                   // unit offset within tile (A)
    const int agate = m16 & 3;                   // gate of this lane's A row

    // ---- A fragments: 7 tiles x 4 k-chunks, pre-scaled f16 ----
    // afrag[tt][c][j] = W'[unit 4(7w+tt)+aoff, gate agate][32c + 8*q4 + j]
    const float wsA = (agate == 2) ? (-2.0f * LOG2E) : (-LOG2E);
    v8h afrag[7][4];
    #pragma unroll
    for (int tt = 0; tt < 7; ++tt) {
        const int t  = 7 * w + tt;
        const int ut = 4 * t + aoff;
        const bool uv = (ut < H110);
        const int rbase = uv ? (ut + H110 * agate) * H110 : 0;
        #pragma unroll
        for (int c = 0; c < 4; ++c) {
            v8h f;
            #pragma unroll
            for (int jj = 0; jj < 8; ++jj) {
                const int k = 32 * c + 8 * q4 + jj;
                const float val = (uv && k < H110) ? W_hh[rbase + k] * wsA : 0.0f;
                f[jj] = (_Float16)val;
            }
            afrag[tt][c] = f;
        }
    }

    // ---- owner-lane constants: lane n<7 owns unit 28w + 4n + q4 ----
    const int  n     = m16;
    const int  uown  = 28 * w + 4 * n + q4;
    const bool valid = (n < 7) && (uown < H110);
    float bvp[4], wvp[4];
    #pragma unroll
    for (int g = 0; g < 4; ++g) {
        const float ws = (g == 2) ? (-2.0f * LOG2E) : (-LOG2E);
        bvp[g] = valid ? b[uown + H110 * g]    * ws : 0.0f;
        wvp[g] = valid ? W_ih[uown + H110 * g] * ws : 0.0f;
    }
    float creg = valid ? c0[uown] : 0.0f;
    float hreg = valid ? h0[uown] : 0.0f;
    const float wpn = valid ? (-LOG2E) * W_p[uown] : 0.0f;
    const float bpn = (-LOG2E) * b_p[0];

    for (int i = tid; i < 256;  i += NT) { s_h16[i] = (_Float16)0.f; s_pbuf[i] = 0.0f; }
    for (int i = tid; i < T784; i += NT) s_x[i] = x[bb * T784 + i];
    __syncthreads();
    if (tid < H110) s_h16[tid] = (_Float16)h0[tid];   // buf0 init
    __syncthreads();

    float u_prev = 1.0f;                         // replicated per-wave (identical)
    int   cnt    = 0;

    auto step = [&](const _Float16* hb, _Float16* hn,
                    const float* pp, float* pn, int t, bool first) {
        // ---- issue LDS reads first ----
        const float p0 = pp[l], p1 = pp[l + 64];
        const float xt = s_x[t];
        const v8h bf0 = *(const v8h*)(hb +  0 + 8 * q4);   // B[k][*]: h bcast
        const v8h bf1 = *(const v8h*)(hb + 32 + 8 * q4);
        const v8h bf2 = *(const v8h*)(hb + 64 + 8 * q4);
        const v8h bf3 = *(const v8h*)(hb + 96 + 8 * q4);

        // ---- 28 mfma: 7 tiles x 4 k-chunks (acc init via zero C) ----
        const v4f zz = {0.f, 0.f, 0.f, 0.f};
#define TILE(i) \
        v4f acc##i = __builtin_amdgcn_mfma_f32_16x16x32_f16(afrag[i][0], bf0, zz, 0, 0, 0); \
        acc##i = __builtin_amdgcn_mfma_f32_16x16x32_f16(afrag[i][1], bf1, acc##i, 0, 0, 0); \
        acc##i = __builtin_amdgcn_mfma_f32_16x16x32_f16(afrag[i][2], bf2, acc##i, 0, 0, 0); \
        acc##i = __builtin_amdgcn_mfma_f32_16x16x32_f16(afrag[i][3], bf3, acc##i, 0, 0, 0);
        TILE(0) TILE(1) TILE(2) TILE(3) TILE(4) TILE(5) TILE(6)
#undef TILE

        // ---- pipelined du_{t-1} -> u_t (overlaps the mfma block) ----
        float u_now;
        if (first) {
            u_now = 1.0f;                        // u0 = 1
        } else {
            float v = p0 + p1;
            v = add_q1(v); v = add_q2(v); v = add_hm(v);
            v = add_rm(v); v = add_b15(v); v = add_b31(v);
            const float tot = __int_as_float(
                __builtin_amdgcn_readlane(__float_as_int(v), 63));
            const float du = frcp(1.0f + fexp2(tot + bpn));      // sigm
            u_now = (u_prev > 0.5f) ? du
                                    : (u_prev + fminf(du, 1.0f - u_prev));
        }
        const bool up = u_now > 0.5f;            // == round-half-even on [0,1]
        cnt += up ? 1 : 0;
        u_prev = u_now;

        // ---- owner lane selects its tile's acc (all C cols identical) ----
        float g0 = acc0[0], g1 = acc0[1], g2 = acc0[2], g3 = acc0[3];
#define PICK(c) { const bool m = (n == c); \
        g0 = m ? acc##c[0] : g0; g1 = m ? acc##c[1] : g1; \
        g2 = m ? acc##c[2] : g2; g3 = m ? acc##c[3] : g3; }
        PICK(1) PICK(2) PICK(3) PICK(4) PICK(5) PICK(6)
#undef PICK

        // ---- activations (weights pre-scaled: sigm = rcp(1+exp2(z))) ----
        const float zi = fmaf(xt, wvp[0], g0 + bvp[0]);
        const float zf = fmaf(xt, wvp[1], g1 + bvp[1]);
        const float zg = fmaf(xt, wvp[2], g2 + bvp[2]);
        const float zo = fmaf(xt, wvp[3], g3 + bvp[3]);
        const float gi = frcp(1.0f + fexp2(zi));
        const float gf = frcp(1.0f + fexp2(zf));
        const float gg = fmaf(2.0f, frcp(1.0f + fexp2(zg)), -1.0f);  // tanh
        const float go = frcp(1.0f + fexp2(zo));

        const float c_new = fmaf(gf, creg, gi * gg);
        const float th    = fmaf(2.0f, frcp(1.0f + fexp2(c_new * (-2.0f * LOG2E))), -1.0f);
        const float h_new = go * th;
        creg = up ? c_new : creg;                // ub is exactly 0/1
        hreg = up ? h_new : hreg;
        if (valid) {
            hn[uown] = (_Float16)hreg;
            pn[uown] = creg * wpn;               // next step's du input
        }
        __syncthreads();                         // the ONLY barrier per step
    };

    _Float16* const h0b = s_h16;
    _Float16* const h1b = s_h16 + 128;
    float* const p0b = s_pbuf;
    float* const p1b = s_pbuf + 128;

    step(h0b, h1b, p0b, p1b, 0, true);           // peeled: no du before step 0
    step(h1b, h0b, p1b, p0b, 1, false);
    step(h0b, h1b, p0b, p1b, 2, false);
    step(h1b, h0b, p1b, p0b, 3, false);
    for (int t = 4; t < T784; t += 4) {
        step(h0b, h1b, p0b, p1b, t,     false);
        step(h1b, h0b, p1b, p0b, t + 1, false);
        step(h0b, h1b, p0b, p1b, t + 2, false);
        step(h1b, h0b, p1b, p0b, t + 3, false);
    }

    // epilogue: final h is in buffer 0 (t=783 writes buf 0)
    if (tid < NCLS) {
        float acc = b_fc[tid];
        for (int k = 0; k < H110; ++k)
            acc = fmaf((float)s_h16[k], W_fc[tid * H110 + k], acc);
        out[bb * NCLS + tid] = acc;
    }
    if (tid == 0)
        atomicAdd(out + 256 * NCLS, (float)cnt); // total_u at flat index 2560
}

__global__ void zero_tail_kernel(float* out) {
    if (threadIdx.x == 0) out[256 * NCLS] = 0.0f;   // d_out is poisoned 0xAA
}

extern "C" void kernel_launch(void* const* d_in, const int* in_sizes, int n_in,
                              void* d_out, int out_size, void* d_ws, size_t ws_size,
                              hipStream_t stream) {
    const float* x    = (const float*)d_in[0];
    const float* W_ih = (const float*)d_in[1];
    const float* W_hh = (const float*)d_in[2];
    const float* b    = (const float*)d_in[3];
    const float* W_p  = (const float*)d_in[4];
    const float* b_p  = (const float*)d_in[5];
    const float* h0   = (const float*)d_in[6];
    const float* c0   = (const float*)d_in[7];
    const float* W_fc = (const float*)d_in[8];
    const float* b_fc = (const float*)d_in[9];
    float* out = (float*)d_out;

    zero_tail_kernel<<<1, 64, 0, stream>>>(out);
    skiplstm_kernel<<<256, NT, 0, stream>>>(x, W_ih, W_hh, b, W_p, b_p,
                                            h0, c0, W_fc, b_fc, out);
}